// Round 9
// baseline (428.285 us; speedup 1.0000x reference)
//
#include <hip/hip_runtime.h>

#define K_CODES 1024
#define D_DIM   256
#define N_VEC   32768
#define BETA    0.25f
#define DECAY   0.99f
#define EPSV    1e-5f

// d_out layout (float32), offsets in elements
#define OFF_ZQ   0          // parks zf[n][d] (k_trans -> k_main/k_fix/k_dw2), overwritten by k_epi
#define OFF_IDX  8388608
#define OFF_LOSS 8421376
#define OFF_EMB  8421377
#define OFF_CS   8683521    // counts -> new_cs (k_scan, in place)
#define OFF_EMAW 8684545    // B_swz fp16 (at +3 for 16B align) until k_zero; then dw -> new_ema_w

// ws layout (floats / ints), ~5.7 MB
#define WS_EMBT    0        // embT[d][j] fp32
#define WS_ENORM   262144   // 1024
#define WS_ELOMAX  263168
#define WS_EHIMAX  263169
#define WS_FIXCNT  263170
#define WS_S2      263172   // 32768 rows x 8 jc x float4 (16B-aligned)
#define WS_ZN2     1311748  // 32768
#define WS_ZLO2    1344516  // 32768 (contiguous after ZN2)
#define WS_FIXLIST 1377284  // 32768 ints; reused as BUCKET
#define WS_OFF     1410052
#define WS_POS     1411076
#define WS_CNT     1412100
#define WS_CHTAB   1413124  // 2048
#define WS_TC      1415172

#define CHUNK 32

typedef _Float16 f16;
typedef f16   f16x4 __attribute__((ext_vector_type(4)));
typedef f16   f16x8 __attribute__((ext_vector_type(8)));
typedef float f32x4 __attribute__((ext_vector_type(4)));

__device__ __forceinline__ void gll16(const void* g, void* l) {
    __builtin_amdgcn_global_load_lds(
        (const __attribute__((address_space(1))) unsigned int*)g,
        (__attribute__((address_space(3))) unsigned int*)l, 16, 0, 0);
}

__device__ inline void top2_fold(float v, int j, float& d1, int& j1, float& d2, int& j2) {
    if (v < d1 || (v == d1 && j < j1)) { d2 = d1; j2 = j1; d1 = v; j1 = j; }
    else if (v < d2 || (v == d2 && j < j2)) { d2 = v; j2 = j; }
}
__device__ inline void top2_merge(float& d1, int& j1, float& d2, int& j2,
                                  float od1, int oj1, float od2, int oj2) {
    if (od1 < d1 || (od1 == d1 && oj1 < j1)) {
        float nd2; int nj2;
        if (d1 < od2 || (d1 == od2 && j1 < oj2)) { nd2 = d1; nj2 = j1; }
        else { nd2 = od2; nj2 = oj2; }
        d2 = nd2; j2 = nj2; d1 = od1; j1 = oj1;
    } else {
        if (od1 < d2 || (od1 == d2 && oj1 < j2)) { d2 = od1; j2 = oj1; }
    }
}

// ---------------------------------------------------------------- init
__global__ void k_init(float* __restrict__ out, float* __restrict__ ws) {
    int i = blockIdx.x * 1024 + threadIdx.x;     // 64 blocks x 1024
    ws[WS_ZN2 + i] = 0.f;                        // covers ZN2 + ZLO2
    if (i < K_CODES) out[OFF_CS + i] = 0.f;
    if (i == 0) {
        out[OFF_LOSS] = 0.f;
        ws[WS_ELOMAX] = 0.f;
        ws[WS_EHIMAX] = 0.f;
        *(int*)(ws + WS_FIXCNT) = 0;
    }
}

// ------------------------------------------------- embT + enorm + elomax/ehimax
__global__ void k_prep(const float* __restrict__ emb, float* __restrict__ ws) {
    int j    = blockIdx.x * 4 + (threadIdx.x >> 6);   // 256 blocks
    int lane = threadIdx.x & 63;
    float4 v = reinterpret_cast<const float4*>(emb + j * D_DIM)[lane];
    ws[(lane * 4 + 0) * 1024 + j] = v.x;
    ws[(lane * 4 + 1) * 1024 + j] = v.y;
    ws[(lane * 4 + 2) * 1024 + j] = v.z;
    ws[(lane * 4 + 3) * 1024 + j] = v.w;
    float s = v.x * v.x + v.y * v.y + v.z * v.z + v.w * v.w;
    float hx = (float)(f16)v.x, hy = (float)(f16)v.y;
    float hz = (float)(f16)v.z, hw = (float)(f16)v.w;
    float lx = v.x - hx, ly = v.y - hy, lz = v.z - hz, lw = v.w - hw;
    float sl = lx * lx + ly * ly + lz * lz + lw * lw;
    float sh = hx * hx + hy * hy + hz * hz + hw * hw;
    #pragma unroll
    for (int o = 32; o > 0; o >>= 1) {
        s  += __shfl_xor(s,  o, 64);
        sl += __shfl_xor(sl, o, 64);
        sh += __shfl_xor(sh, o, 64);
    }
    if (lane == 0) {
        ws[WS_ENORM + j] = s;
        atomicMax((int*)(ws + WS_ELOMAX), __float_as_int(sqrtf(sl)));
        atomicMax((int*)(ws + WS_EHIMAX), __float_as_int(sqrtf(sh)));
    }
}

// ------------------------------------------------- B_swz (fp16 fragment order, 16B-aligned base)
__global__ void k_prep_b(const float* __restrict__ emb, float* __restrict__ out) {
    int slot = blockIdx.x * 256 + threadIdx.x;   // 128 blocks -> 32768 slots
    int lane = slot & 63;
    int kbjt = slot >> 6;
    int kb   = kbjt & 7;                         // k-block of 32 (K=256)
    int jt   = kbjt >> 3;                        // j-tile of 16
    int j    = jt * 16 + (lane & 15);
    int d0   = kb * 32 + (lane >> 4) * 8;
    float4 e0 = *reinterpret_cast<const float4*>(emb + j * D_DIM + d0);
    float4 e1 = *reinterpret_cast<const float4*>(emb + j * D_DIM + d0 + 4);
    f16x8 w;
    w[0] = (f16)e0.x; w[1] = (f16)e0.y; w[2] = (f16)e0.z; w[3] = (f16)e0.w;
    w[4] = (f16)e1.x; w[5] = (f16)e1.y; w[6] = (f16)e1.z; w[7] = (f16)e1.w;
    f16* dst = (f16*)(out + OFF_EMAW + 3);       // +3 floats -> 16B aligned
    *reinterpret_cast<f16x8*>(dst + slot * 8) = w;
}

// ------------------------------------------------- zf[n][d] transpose + row norms
__global__ void k_trans(const float* __restrict__ z, float* __restrict__ out,
                        float* __restrict__ ws) {
    __shared__ float tile[32][33];
    int bid = blockIdx.x;                        // 8192 blocks
    int b   = bid >> 8;
    int rem = bid & 255;
    int d0  = (rem >> 5) * 32;
    int hw0 = (rem & 31) * 32;
    const int tid = threadIdx.x;                 // 256
    #pragma unroll
    for (int rep = 0; rep < 4; ++rep) {
        int elem = rep * 256 + tid;
        int dl = elem >> 5, hwl = elem & 31;
        tile[dl][hwl] = z[b * (D_DIM * 1024) + (d0 + dl) * 1024 + hw0 + hwl];
    }
    __syncthreads();
    #pragma unroll
    for (int rep = 0; rep < 4; ++rep) {
        int elem = rep * 256 + tid;
        int hwl = elem >> 5, dl = elem & 31;
        out[OFF_ZQ + (long)(b * 1024 + hw0 + hwl) * 256 + d0 + dl] = tile[dl][hwl];
    }
    if (tid < 32) {
        float sn = 0.f, sl = 0.f;
        #pragma unroll 8
        for (int dl = 0; dl < 32; ++dl) {
            float v  = tile[dl][tid];
            float lo = v - (float)(f16)v;
            sn += v * v; sl += lo * lo;
        }
        int n = b * 1024 + hw0 + tid;
        atomicAdd(ws + WS_ZN2 + n, sn);
        atomicAdd(ws + WS_ZLO2 + n, sl);
    }
}

// ---------------------------------------------------------------- main (MFMA, jc loop inside,
//                              A in regs, B double-buffered via global_load_lds)
__global__ __launch_bounds__(256, 2)
void k_main(float* __restrict__ out, float* __restrict__ ws) {
    __shared__ f16   Bl[2][4096];     // 2 x 8 KB: per kb, 8 jt-segments of 1 KB
    __shared__ float els_s[K_CODES];  // 4 KB

    const int tid  = threadIdx.x;     // 256 = 4 waves
    const int lane = tid & 63;
    const int w    = tid >> 6;
    const int n0   = blockIdx.x * 64; // 512 blocks
    const float* zf = out + OFF_ZQ;
    const f16* Bw = (const f16*)(out + OFF_EMAW + 3);

    // ---- A fragments straight to registers (each element read exactly once)
    const int arow = n0 + w * 16 + (lane & 15);
    const int aoff = (lane >> 4) * 8;
    f16x8 a[8];
    #pragma unroll
    for (int kb = 0; kb < 8; ++kb) {
        float4 p0 = *reinterpret_cast<const float4*>(zf + (long)arow * 256 + kb * 32 + aoff);
        float4 p1 = *reinterpret_cast<const float4*>(zf + (long)arow * 256 + kb * 32 + aoff + 4);
        a[kb] = (f16x8){(f16)p0.x, (f16)p0.y, (f16)p0.z, (f16)p0.w,
                        (f16)p1.x, (f16)p1.y, (f16)p1.z, (f16)p1.w};
    }
    #pragma unroll
    for (int r = 0; r < 4; ++r) els_s[r * 256 + tid] = ws[WS_ENORM + r * 256 + tid];

    // ---- stage (jc=0, kb=0) into buf 0: wave w stages jt = 2w, 2w+1
#define STAGE_B(jcs, kbs, bb)                                                     \
    {                                                                             \
        const f16* g0 = Bw + ((size_t)(((jcs) * 64 + (w * 2) * 8 + (kbs)) * 64 + lane)) * 8; \
        gll16(g0,             &Bl[bb][(w * 2)     * 512]);                        \
        gll16(g0 + 4096,      &Bl[bb][(w * 2 + 1) * 512]);                        \
    }
    STAGE_B(0, 0, 0);
    __syncthreads();   // drains A loads + staged B(0,0)

    f32x4 acc[8];
    #pragma unroll
    for (int q = 0; q < 8; ++q) acc[q] = (f32x4){0.f, 0.f, 0.f, 0.f};

    for (int jc = 0; jc < 8; ++jc) {
        #pragma unroll
        for (int kb = 0; kb < 8; ++kb) {
            const int buf = kb & 1;
            // stage next chunk into other buffer (in flight across the MFMAs)
            if (kb < 7)            STAGE_B(jc, kb + 1, buf ^ 1)
            else if (jc < 7)       STAGE_B(jc + 1, 0, buf ^ 1)
            // compute current chunk
            #pragma unroll
            for (int q = 0; q < 8; ++q) {
                f16x8 bq = *reinterpret_cast<const f16x8*>(&Bl[buf][q * 512 + lane * 8]);
                acc[q] = __builtin_amdgcn_mfma_f32_16x16x32_f16(a[kb], bq, acc[q], 0, 0, 0);
            }
            __syncthreads();       // one vmcnt-drain + barrier per chunk
        }

        // ---- per-row top-2 over this jc's 128 j -> S2 (overlaps next jc's staging)
        #pragma unroll
        for (int r = 0; r < 4; ++r) {
            float d1 = 3.4e38f, d2 = 3.4e38f; int j1 = -1, j2 = -1;
            #pragma unroll
            for (int q = 0; q < 8; ++q) {
                int jl = q * 16 + (lane & 15);
                float v = els_s[jc * 128 + jl] - 2.f * acc[q][r];
                top2_fold(v, jc * 128 + jl, d1, j1, d2, j2);
            }
            #pragma unroll
            for (int s = 1; s < 16; s <<= 1) {
                float od1 = __shfl_xor(d1, s, 64); int oj1 = __shfl_xor(j1, s, 64);
                float od2 = __shfl_xor(d2, s, 64); int oj2 = __shfl_xor(j2, s, 64);
                top2_merge(d1, j1, d2, j2, od1, oj1, od2, oj2);
            }
            if ((lane & 15) == 0) {
                int row = n0 + w * 16 + (lane >> 4) * 4 + r;
                *reinterpret_cast<float4*>(ws + WS_S2 + ((size_t)row * 8 + jc) * 4) =
                    (float4){d1, (float)j1, d2, (float)j2};
            }
        }
        #pragma unroll
        for (int q = 0; q < 8; ++q) acc[q] = (f32x4){0.f, 0.f, 0.f, 0.f};
    }
#undef STAGE_B
}

// ---------------------------------------------------------------- global top-2 merge + flag
__global__ void k_merge(float* __restrict__ ws, float* __restrict__ out) {
    int n = blockIdx.x * 256 + threadIdx.x;      // 128 blocks
    const float4* S2 = reinterpret_cast<const float4*>(ws + WS_S2) + (size_t)n * 8;
    float4 e0 = S2[0];
    float d1 = e0.x; int j1 = (int)e0.y; float d2 = e0.z; int j2 = (int)e0.w;
    #pragma unroll
    for (int c = 1; c < 8; ++c) {
        float4 e = S2[c];
        top2_merge(d1, j1, d2, j2, e.x, (int)e.y, e.z, (int)e.w);
    }
    out[OFF_IDX + n] = (float)j1;
    float margin = 4.f * (sqrtf(ws[WS_ZLO2 + n]) * ws[WS_EHIMAX] +
                          sqrtf(ws[WS_ZN2 + n])  * ws[WS_ELOMAX]) + 0.05f;
    if (d2 - d1 <= margin) {
        int p = atomicAdd((int*)(ws + WS_FIXCNT), 1);
        ((int*)(ws + WS_FIXLIST))[p] = n;
    }
}

// ---------------------------------------------------------------- exact recompute (batched 8 rows)
__global__ void k_fix(const float* __restrict__ ws_c, float* __restrict__ out) {
    __shared__ float zr[8][256];
    __shared__ float rd[8][4]; __shared__ int rj[8][4];
    const int tid = threadIdx.x;                 // 256
    const int cnt = *(const int*)(ws_c + WS_FIXCNT);
    const int* fixlist = (const int*)(ws_c + WS_FIXLIST);
    const int groups = (cnt + 7) >> 3;
    const float4 en = *reinterpret_cast<const float4*>(ws_c + WS_ENORM + tid * 4);

    for (int g = blockIdx.x; g < groups; g += gridDim.x) {
        int nrow[8];
        #pragma unroll
        for (int r = 0; r < 8; ++r) {
            int slot = g * 8 + r;
            nrow[r] = (slot < cnt) ? fixlist[slot] : -1;
        }
        #pragma unroll
        for (int r = 0; r < 8; ++r)
            zr[r][tid] = (nrow[r] >= 0) ? out[OFF_ZQ + (long)nrow[r] * 256 + tid] : 0.f;
        __syncthreads();

        float acc[8][4];
        #pragma unroll
        for (int r = 0; r < 8; ++r)
            #pragma unroll
            for (int q = 0; q < 4; ++q) acc[r][q] = 0.f;
        for (int d = 0; d < 256; ++d) {
            float4 e = *reinterpret_cast<const float4*>(ws_c + WS_EMBT + d * 1024 + tid * 4);
            #pragma unroll
            for (int r = 0; r < 8; ++r) {
                float zd = zr[r][d];
                acc[r][0] += zd * e.x; acc[r][1] += zd * e.y;
                acc[r][2] += zd * e.z; acc[r][3] += zd * e.w;
            }
        }
        #pragma unroll
        for (int r = 0; r < 8; ++r) {
            float best = 3.4e38f; int bj = 0;
            #pragma unroll
            for (int q = 0; q < 4; ++q) {
                int j = tid * 4 + q;
                float v = ((const float*)&en)[q] - 2.f * acc[r][q];
                if (v < best || (v == best && j < bj)) { best = v; bj = j; }
            }
            #pragma unroll
            for (int o = 1; o < 64; o <<= 1) {
                float ov = __shfl_xor(best, o, 64);
                int   oj = __shfl_xor(bj, o, 64);
                if (ov < best || (ov == best && oj < bj)) { best = ov; bj = oj; }
            }
            if ((tid & 63) == 0) { rd[r][tid >> 6] = best; rj[r][tid >> 6] = bj; }
        }
        __syncthreads();
        if (tid < 8) {
            int r = tid;
            float v = rd[r][0]; int j = rj[r][0];
            #pragma unroll
            for (int ww = 1; ww < 4; ++ww)
                if (rd[r][ww] < v || (rd[r][ww] == v && rj[r][ww] < j)) { v = rd[r][ww]; j = rj[r][ww]; }
            int slot = g * 8 + r;
            if (slot < cnt) out[OFF_IDX + fixlist[slot]] = (float)j;
        }
        __syncthreads();
    }
}

// ---------------------------------------------------------------- counts
__global__ void k_count(float* __restrict__ out) {
    int n = blockIdx.x * 256 + threadIdx.x;      // 128 blocks
    int j = (int)out[OFF_IDX + n];
    atomicAdd(out + OFF_CS + j, 1.0f);
}

// ---------------------------------------------------------------- scan: offsets + chunk table + new_cs
__global__ void k_scan(const float* __restrict__ ema_cs, float* __restrict__ ws,
                       float* __restrict__ out) {
    __shared__ float s[K_CODES];
    int tid = threadIdx.x;                       // 1024
    float cntf = out[OFF_CS + tid];
    int   cnt  = (int)cntf;
    float raw  = ema_cs[tid] * DECAY + 0.01f * cntf;

    s[tid] = cntf;
    __syncthreads();
    for (int off = 1; off < 1024; off <<= 1) {
        float v = (tid >= off) ? s[tid - off] : 0.f;
        __syncthreads();
        s[tid] += v;
        __syncthreads();
    }
    int excl = (int)(s[tid] - cntf);
    ((int*)(ws + WS_OFF))[tid] = excl;
    ((int*)(ws + WS_POS))[tid] = excl;
    ((int*)(ws + WS_CNT))[tid] = cnt;
    __syncthreads();

    int nch = (cnt + CHUNK - 1) / CHUNK;
    s[tid] = (float)nch;
    __syncthreads();
    for (int off = 1; off < 1024; off <<= 1) {
        float v = (tid >= off) ? s[tid - off] : 0.f;
        __syncthreads();
        s[tid] += v;
        __syncthreads();
    }
    int chexcl = (int)s[tid] - nch;
    int* chtab = (int*)(ws + WS_CHTAB);
    for (int k = 0; k < nch; ++k)
        chtab[chexcl + k] = (tid << 16) | k;
    if (tid == 1023) *(int*)(ws + WS_TC) = chexcl + nch;
    __syncthreads();

    s[tid] = raw;
    __syncthreads();
    for (int st = 512; st > 0; st >>= 1) {
        if (tid < st) s[tid] += s[tid + st];
        __syncthreads();
    }
    float ntot = s[0];
    out[OFF_CS + tid] = (raw + EPSV) / (ntot + K_CODES * EPSV) * ntot;
}

// ---------------------------------------------------------------- scatter into buckets
__global__ void k_scatter(const float* __restrict__ out_c, float* __restrict__ ws) {
    int n = blockIdx.x * 256 + threadIdx.x;      // 128 blocks
    int j = (int)out_c[OFF_IDX + n];
    int p = atomicAdd((int*)(ws + WS_POS) + j, 1);
    ((int*)(ws + WS_FIXLIST))[p] = n;
}

// ---------------------------------------------------------------- zero dw accumulator
__global__ void k_zero(float* __restrict__ out) {
    int i = blockIdx.x * 256 + threadIdx.x;      // 256 blocks
    *reinterpret_cast<float4*>(out + OFF_EMAW + i * 4) = (float4){0.f, 0.f, 0.f, 0.f};
}

// ---------------------------------------------------------------- dw partial sums (chunked)
__global__ void k_dw2(const float* __restrict__ ws, float* __restrict__ out) {
    __shared__ int midx[CHUNK];
    const int b = blockIdx.x;                    // 2048 blocks
    if (b >= *(const int*)(ws + WS_TC)) return;
    const int tab = ((const int*)(ws + WS_CHTAB))[b];
    const int j   = tab >> 16;
    const int lc  = tab & 0xffff;
    const int off = ((const int*)(ws + WS_OFF))[j];
    const int cnt = ((const int*)(ws + WS_CNT))[j];
    const int base = lc * CHUNK;
    const int m    = min(CHUNK, cnt - base);
    const int tid  = threadIdx.x;                // 256: d = tid
    if (tid < CHUNK)
        midx[tid] = (tid < m) ? ((const int*)(ws + WS_FIXLIST))[off + base + tid] : 0;
    __syncthreads();
    float acc = 0.f;
    for (int i = 0; i < m; ++i)
        acc += out[OFF_ZQ + (long)midx[i] * 256 + tid];
    atomicAdd(out + OFF_EMAW + j * 256 + tid, acc);
}

// ---------------------------------------------------------------- new_ema_w + new_embedding
__global__ void k_emb2(const float* __restrict__ ema_w, float* __restrict__ out) {
    int i4 = blockIdx.x * 256 + threadIdx.x;     // 256 blocks -> 65536 float4
    int j  = i4 >> 6;
    float4 dw = *reinterpret_cast<float4*>(out + OFF_EMAW + i4 * 4);
    float4 ew = *reinterpret_cast<const float4*>(ema_w + i4 * 4);
    float inv = 1.f / out[OFF_CS + j];
    float4 nw = {ew.x * DECAY + 0.01f * dw.x, ew.y * DECAY + 0.01f * dw.y,
                 ew.z * DECAY + 0.01f * dw.z, ew.w * DECAY + 0.01f * dw.w};
    *reinterpret_cast<float4*>(out + OFF_EMAW + i4 * 4) = nw;
    float4 nb = {nw.x * inv, nw.y * inv, nw.z * inv, nw.w * inv};
    *reinterpret_cast<float4*>(out + OFF_EMB + i4 * 4) = nb;
}

// ---------------------------------------------------------------- z_q + loss
__global__ void k_epi(const float* __restrict__ z, const float* __restrict__ emb,
                      float* __restrict__ out) {
    __shared__ float erows[32][257];
    __shared__ int js[32];
    const int tid = threadIdx.x;                 // 256
    const int n0  = blockIdx.x * 32;             // 1024 blocks
    const int b   = n0 >> 10;
    const int hw0 = n0 & 1023;
    if (tid < 32) js[tid] = (int)out[OFF_IDX + n0 + tid];
    __syncthreads();
    #pragma unroll 4
    for (int r = 0; r < 32; ++r)
        erows[r][tid] = emb[js[r] * D_DIM + tid];
    __syncthreads();
    const long zqb = (long)b * (D_DIM * 1024) + hw0;
    float ls = 0.f;
    #pragma unroll 4
    for (int rep = 0; rep < 32; ++rep) {
        int elem = rep * 256 + tid;
        int d    = elem >> 5;
        int nl   = elem & 31;
        float zq = erows[nl][d];
        float zv = z[zqb + d * 1024 + nl];
        out[OFF_ZQ + zqb + d * 1024 + nl] = zq;
        float df = zq - zv; ls += df * df;
    }
    #pragma unroll
    for (int o = 32; o > 0; o >>= 1) ls += __shfl_xor(ls, o, 64);
    if ((tid & 63) == 0)
        atomicAdd(out + OFF_LOSS, ls * (BETA / (float)(N_VEC * D_DIM)));
}

// ---------------------------------------------------------------- launch
extern "C" void kernel_launch(void* const* d_in, const int* in_sizes, int n_in,
                              void* d_out, int out_size, void* d_ws, size_t ws_size,
                              hipStream_t stream) {
    const float* z      = (const float*)d_in[0];
    const float* emb    = (const float*)d_in[1];
    const float* ema_cs = (const float*)d_in[2];
    const float* ema_w  = (const float*)d_in[3];
    float* out = (float*)d_out;
    float* ws  = (float*)d_ws;                   // ~5.7 MB used

    hipLaunchKernelGGL(k_init,    dim3(64),   dim3(1024), 0, stream, out, ws);
    hipLaunchKernelGGL(k_prep,    dim3(256),  dim3(256),  0, stream, emb, ws);
    hipLaunchKernelGGL(k_prep_b,  dim3(128),  dim3(256),  0, stream, emb, out);
    hipLaunchKernelGGL(k_trans,   dim3(8192), dim3(256),  0, stream, z, out, ws);
    hipLaunchKernelGGL(k_main,    dim3(512),  dim3(256),  0, stream, out, ws);
    hipLaunchKernelGGL(k_merge,   dim3(128),  dim3(256),  0, stream, ws, out);
    hipLaunchKernelGGL(k_fix,     dim3(256),  dim3(256),  0, stream, ws, out);
    hipLaunchKernelGGL(k_count,   dim3(128),  dim3(256),  0, stream, out);
    hipLaunchKernelGGL(k_scan,    dim3(1),    dim3(1024), 0, stream, ema_cs, ws, out);
    hipLaunchKernelGGL(k_scatter, dim3(128),  dim3(256),  0, stream, out, ws);
    hipLaunchKernelGGL(k_zero,    dim3(256),  dim3(256),  0, stream, out);
    hipLaunchKernelGGL(k_dw2,     dim3(2048), dim3(256),  0, stream, ws, out);
    hipLaunchKernelGGL(k_emb2,    dim3(256),  dim3(256),  0, stream, ema_w, out);
    hipLaunchKernelGGL(k_epi,     dim3(1024), dim3(256),  0, stream, z, emb, out);
}

// Round 10
// 421.398 us; speedup vs baseline: 1.0163x; 1.0163x over previous
//
#include <hip/hip_runtime.h>

#define K_CODES 1024
#define D_DIM   256
#define N_VEC   32768
#define BETA    0.25f
#define DECAY   0.99f
#define EPSV    1e-5f

// d_out layout (float32), offsets in elements
#define OFF_ZQ   0          // parks zf[n][d] (k_trans -> k_main/k_fix/k_dw2), overwritten by k_epi
#define OFF_IDX  8388608
#define OFF_LOSS 8421376
#define OFF_EMB  8421377
#define OFF_CS   8683521    // counts -> new_cs (k_scan, in place)
#define OFF_EMAW 8684545    // B_swz fp16 (at +3 for 16B align) until k_zero; then dw -> new_ema_w

// ws layout (floats / ints), ~5.7 MB
#define WS_EMBT    0        // embT[d][j] fp32
#define WS_ENORM   262144   // 1024
#define WS_ELOMAX  263168
#define WS_EHIMAX  263169
#define WS_FIXCNT  263170
#define WS_S2      263172   // 32768 rows x 8 jc x float4 (16B-aligned)
#define WS_ZN2     1311748  // 32768
#define WS_ZLO2    1344516  // 32768 (contiguous after ZN2)
#define WS_FIXLIST 1377284  // 32768 ints; reused as BUCKET
#define WS_OFF     1410052
#define WS_POS     1411076
#define WS_CNT     1412100
#define WS_CHTAB   1413124  // 2048
#define WS_TC      1415172

#define CHUNK 32

typedef _Float16 f16;
typedef f16   f16x4 __attribute__((ext_vector_type(4)));
typedef f16   f16x8 __attribute__((ext_vector_type(8)));
typedef float f32x4 __attribute__((ext_vector_type(4)));

__device__ __forceinline__ void gll16(const void* g, void* l) {
    __builtin_amdgcn_global_load_lds(
        (const __attribute__((address_space(1))) unsigned int*)g,
        (__attribute__((address_space(3))) unsigned int*)l, 16, 0, 0);
}

__device__ inline void top2_fold(float v, int j, float& d1, int& j1, float& d2, int& j2) {
    if (v < d1 || (v == d1 && j < j1)) { d2 = d1; j2 = j1; d1 = v; j1 = j; }
    else if (v < d2 || (v == d2 && j < j2)) { d2 = v; j2 = j; }
}
__device__ inline void top2_merge(float& d1, int& j1, float& d2, int& j2,
                                  float od1, int oj1, float od2, int oj2) {
    if (od1 < d1 || (od1 == d1 && oj1 < j1)) {
        float nd2; int nj2;
        if (d1 < od2 || (d1 == od2 && j1 < oj2)) { nd2 = d1; nj2 = j1; }
        else { nd2 = od2; nj2 = oj2; }
        d2 = nd2; j2 = nj2; d1 = od1; j1 = oj1;
    } else {
        if (od1 < d2 || (od1 == d2 && oj1 < j2)) { d2 = od1; j2 = oj1; }
    }
}

// ---------------------------------------------------------------- init
__global__ void k_init(float* __restrict__ out, float* __restrict__ ws) {
    int i = blockIdx.x * 1024 + threadIdx.x;     // 64 blocks x 1024
    ws[WS_ZN2 + i] = 0.f;                        // covers ZN2 + ZLO2
    if (i < K_CODES) out[OFF_CS + i] = 0.f;
    if (i == 0) {
        out[OFF_LOSS] = 0.f;
        ws[WS_ELOMAX] = 0.f;
        ws[WS_EHIMAX] = 0.f;
        *(int*)(ws + WS_FIXCNT) = 0;
    }
}

// ------------------------------------------------- embT + enorm + elomax/ehimax
__global__ void k_prep(const float* __restrict__ emb, float* __restrict__ ws) {
    int j    = blockIdx.x * 4 + (threadIdx.x >> 6);   // 256 blocks
    int lane = threadIdx.x & 63;
    float4 v = reinterpret_cast<const float4*>(emb + j * D_DIM)[lane];
    ws[(lane * 4 + 0) * 1024 + j] = v.x;
    ws[(lane * 4 + 1) * 1024 + j] = v.y;
    ws[(lane * 4 + 2) * 1024 + j] = v.z;
    ws[(lane * 4 + 3) * 1024 + j] = v.w;
    float s = v.x * v.x + v.y * v.y + v.z * v.z + v.w * v.w;
    float hx = (float)(f16)v.x, hy = (float)(f16)v.y;
    float hz = (float)(f16)v.z, hw = (float)(f16)v.w;
    float lx = v.x - hx, ly = v.y - hy, lz = v.z - hz, lw = v.w - hw;
    float sl = lx * lx + ly * ly + lz * lz + lw * lw;
    float sh = hx * hx + hy * hy + hz * hz + hw * hw;
    #pragma unroll
    for (int o = 32; o > 0; o >>= 1) {
        s  += __shfl_xor(s,  o, 64);
        sl += __shfl_xor(sl, o, 64);
        sh += __shfl_xor(sh, o, 64);
    }
    if (lane == 0) {
        ws[WS_ENORM + j] = s;
        atomicMax((int*)(ws + WS_ELOMAX), __float_as_int(sqrtf(sl)));
        atomicMax((int*)(ws + WS_EHIMAX), __float_as_int(sqrtf(sh)));
    }
}

// ------------------------------------------------- B_swz (fp16 fragment order, 16B-aligned base)
__global__ void k_prep_b(const float* __restrict__ emb, float* __restrict__ out) {
    int slot = blockIdx.x * 256 + threadIdx.x;   // 128 blocks -> 32768 slots
    int lane = slot & 63;
    int kbjt = slot >> 6;
    int kb   = kbjt & 7;                         // k-block of 32 (K=256)
    int jt   = kbjt >> 3;                        // j-tile of 16
    int j    = jt * 16 + (lane & 15);
    int d0   = kb * 32 + (lane >> 4) * 8;
    float4 e0 = *reinterpret_cast<const float4*>(emb + j * D_DIM + d0);
    float4 e1 = *reinterpret_cast<const float4*>(emb + j * D_DIM + d0 + 4);
    f16x8 w;
    w[0] = (f16)e0.x; w[1] = (f16)e0.y; w[2] = (f16)e0.z; w[3] = (f16)e0.w;
    w[4] = (f16)e1.x; w[5] = (f16)e1.y; w[6] = (f16)e1.z; w[7] = (f16)e1.w;
    f16* dst = (f16*)(out + OFF_EMAW + 3);       // +3 floats -> 16B aligned
    *reinterpret_cast<f16x8*>(dst + slot * 8) = w;
}

// ------------------------------------------------- zf[n][d] transpose + row norms
__global__ void k_trans(const float* __restrict__ z, float* __restrict__ out,
                        float* __restrict__ ws) {
    __shared__ float tile[32][33];
    int bid = blockIdx.x;                        // 8192 blocks
    int b   = bid >> 8;
    int rem = bid & 255;
    int d0  = (rem >> 5) * 32;
    int hw0 = (rem & 31) * 32;
    const int tid = threadIdx.x;                 // 256
    #pragma unroll
    for (int rep = 0; rep < 4; ++rep) {
        int elem = rep * 256 + tid;
        int dl = elem >> 5, hwl = elem & 31;
        tile[dl][hwl] = z[b * (D_DIM * 1024) + (d0 + dl) * 1024 + hw0 + hwl];
    }
    __syncthreads();
    #pragma unroll
    for (int rep = 0; rep < 4; ++rep) {
        int elem = rep * 256 + tid;
        int hwl = elem >> 5, dl = elem & 31;
        out[OFF_ZQ + (long)(b * 1024 + hw0 + hwl) * 256 + d0 + dl] = tile[dl][hwl];
    }
    if (tid < 32) {
        float sn = 0.f, sl = 0.f;
        #pragma unroll 8
        for (int dl = 0; dl < 32; ++dl) {
            float v  = tile[dl][tid];
            float lo = v - (float)(f16)v;
            sn += v * v; sl += lo * lo;
        }
        int n = b * 1024 + hw0 + tid;
        atomicAdd(ws + WS_ZN2 + n, sn);
        atomicAdd(ws + WS_ZLO2 + n, sl);
    }
}

// ---------------------------------------------------------------- main (MFMA, whole-jc dbuf pipeline)
__global__ __launch_bounds__(512, 1)
void k_main(float* __restrict__ out, float* __restrict__ ws) {
    __shared__ f16   Bl[2][32768];    // 2 x 64 KB (one full jc-slice each)
    __shared__ float els_s[K_CODES];  // 4 KB

    const int tid  = threadIdx.x;     // 512 = 8 waves
    const int lane = tid & 63;
    const int w    = tid >> 6;
    const int n0   = blockIdx.x * 128; // 256 blocks -> 1 block/CU
    const float* zf = out + OFF_ZQ;
    const f16* Bw = (const f16*)(out + OFF_EMAW + 3);

    // ---- A fragments straight to registers (each element read exactly once)
    const int arow = n0 + w * 16 + (lane & 15);
    const int aoff = (lane >> 4) * 8;
    f16x8 a[8];
    #pragma unroll
    for (int kb = 0; kb < 8; ++kb) {
        float4 p0 = *reinterpret_cast<const float4*>(zf + (long)arow * 256 + kb * 32 + aoff);
        float4 p1 = *reinterpret_cast<const float4*>(zf + (long)arow * 256 + kb * 32 + aoff + 4);
        a[kb] = (f16x8){(f16)p0.x, (f16)p0.y, (f16)p0.z, (f16)p0.w,
                        (f16)p1.x, (f16)p1.y, (f16)p1.z, (f16)p1.w};
    }
    #pragma unroll
    for (int r = 0; r < 2; ++r) els_s[r * 512 + tid] = ws[WS_ENORM + r * 512 + tid];

    // stage whole jc-slice (64 KB): wave w moves 8 KB as 8 x 1KB gll16
#define STAGE(jcs, bb)                                                        \
    {                                                                         \
        const f16* g0 = Bw + (size_t)(jcs) * 32768 + w * 4096 + lane * 8;     \
        f16* l0 = &Bl[bb][w * 4096];                                          \
        _Pragma("unroll")                                                     \
        for (int i = 0; i < 8; ++i) gll16(g0 + i * 512, l0 + i * 512);        \
    }

    STAGE(0, 0);
    __syncthreads();

    f32x4 acc[8];
    for (int jc = 0; jc < 8; ++jc) {
        const int buf = jc & 1;
        if (jc < 7) STAGE(jc + 1, buf ^ 1);      // 64 KB in flight across this jc's compute

        #pragma unroll
        for (int q = 0; q < 8; ++q) acc[q] = (f32x4){0.f, 0.f, 0.f, 0.f};
        const f16* Bcur = &Bl[buf][0];
        #pragma unroll
        for (int kb = 0; kb < 8; ++kb) {
            #pragma unroll
            for (int q = 0; q < 8; ++q) {
                f16x8 bq = *reinterpret_cast<const f16x8*>(&Bcur[(q * 8 + kb) * 512 + lane * 8]);
                acc[q] = __builtin_amdgcn_mfma_f32_16x16x32_f16(a[kb], bq, acc[q], 0, 0, 0);
            }
        }

        // ---- per-row top-2 over this jc's 128 j -> S2 (VALU; overlaps staging latency)
        #pragma unroll
        for (int r = 0; r < 4; ++r) {
            float d1 = 3.4e38f, d2 = 3.4e38f; int j1 = -1, j2 = -1;
            #pragma unroll
            for (int q = 0; q < 8; ++q) {
                int jl = q * 16 + (lane & 15);
                float v = els_s[jc * 128 + jl] - 2.f * acc[q][r];
                top2_fold(v, jc * 128 + jl, d1, j1, d2, j2);
            }
            #pragma unroll
            for (int s = 1; s < 16; s <<= 1) {
                float od1 = __shfl_xor(d1, s, 64); int oj1 = __shfl_xor(j1, s, 64);
                float od2 = __shfl_xor(d2, s, 64); int oj2 = __shfl_xor(j2, s, 64);
                top2_merge(d1, j1, d2, j2, od1, oj1, od2, oj2);
            }
            if ((lane & 15) == 0) {
                int row = n0 + w * 16 + (lane >> 4) * 4 + r;
                *reinterpret_cast<float4*>(ws + WS_S2 + ((size_t)row * 8 + jc) * 4) =
                    (float4){d1, (float)j1, d2, (float)j2};
            }
        }
        __syncthreads();   // one drain+barrier per jc (9 total)
    }
#undef STAGE
}

// ---------------------------------------------------------------- global top-2 merge + flag
__global__ void k_merge(float* __restrict__ ws, float* __restrict__ out) {
    int n = blockIdx.x * 256 + threadIdx.x;      // 128 blocks
    const float4* S2 = reinterpret_cast<const float4*>(ws + WS_S2) + (size_t)n * 8;
    float4 e0 = S2[0];
    float d1 = e0.x; int j1 = (int)e0.y; float d2 = e0.z; int j2 = (int)e0.w;
    #pragma unroll
    for (int c = 1; c < 8; ++c) {
        float4 e = S2[c];
        top2_merge(d1, j1, d2, j2, e.x, (int)e.y, e.z, (int)e.w);
    }
    out[OFF_IDX + n] = (float)j1;
    float margin = 4.f * (sqrtf(ws[WS_ZLO2 + n]) * ws[WS_EHIMAX] +
                          sqrtf(ws[WS_ZN2 + n])  * ws[WS_ELOMAX]) + 0.05f;
    if (d2 - d1 <= margin) {
        int p = atomicAdd((int*)(ws + WS_FIXCNT), 1);
        ((int*)(ws + WS_FIXLIST))[p] = n;
    }
}

// ---------------------------------------------------------------- exact recompute (batched 8 rows)
__global__ void k_fix(const float* __restrict__ ws_c, float* __restrict__ out) {
    __shared__ float zr[8][256];
    __shared__ float rd[8][4]; __shared__ int rj[8][4];
    const int tid = threadIdx.x;                 // 256
    const int cnt = *(const int*)(ws_c + WS_FIXCNT);
    const int* fixlist = (const int*)(ws_c + WS_FIXLIST);
    const int groups = (cnt + 7) >> 3;
    const float4 en = *reinterpret_cast<const float4*>(ws_c + WS_ENORM + tid * 4);

    for (int g = blockIdx.x; g < groups; g += gridDim.x) {
        int nrow[8];
        #pragma unroll
        for (int r = 0; r < 8; ++r) {
            int slot = g * 8 + r;
            nrow[r] = (slot < cnt) ? fixlist[slot] : -1;
        }
        #pragma unroll
        for (int r = 0; r < 8; ++r)
            zr[r][tid] = (nrow[r] >= 0) ? out[OFF_ZQ + (long)nrow[r] * 256 + tid] : 0.f;
        __syncthreads();

        float acc[8][4];
        #pragma unroll
        for (int r = 0; r < 8; ++r)
            #pragma unroll
            for (int q = 0; q < 4; ++q) acc[r][q] = 0.f;
        for (int d = 0; d < 256; ++d) {
            float4 e = *reinterpret_cast<const float4*>(ws_c + WS_EMBT + d * 1024 + tid * 4);
            #pragma unroll
            for (int r = 0; r < 8; ++r) {
                float zd = zr[r][d];
                acc[r][0] += zd * e.x; acc[r][1] += zd * e.y;
                acc[r][2] += zd * e.z; acc[r][3] += zd * e.w;
            }
        }
        #pragma unroll
        for (int r = 0; r < 8; ++r) {
            float best = 3.4e38f; int bj = 0;
            #pragma unroll
            for (int q = 0; q < 4; ++q) {
                int j = tid * 4 + q;
                float v = ((const float*)&en)[q] - 2.f * acc[r][q];
                if (v < best || (v == best && j < bj)) { best = v; bj = j; }
            }
            #pragma unroll
            for (int o = 1; o < 64; o <<= 1) {
                float ov = __shfl_xor(best, o, 64);
                int   oj = __shfl_xor(bj, o, 64);
                if (ov < best || (ov == best && oj < bj)) { best = ov; bj = oj; }
            }
            if ((tid & 63) == 0) { rd[r][tid >> 6] = best; rj[r][tid >> 6] = bj; }
        }
        __syncthreads();
        if (tid < 8) {
            int r = tid;
            float v = rd[r][0]; int j = rj[r][0];
            #pragma unroll
            for (int ww = 1; ww < 4; ++ww)
                if (rd[r][ww] < v || (rd[r][ww] == v && rj[r][ww] < j)) { v = rd[r][ww]; j = rj[r][ww]; }
            int slot = g * 8 + r;
            if (slot < cnt) out[OFF_IDX + fixlist[slot]] = (float)j;
        }
        __syncthreads();
    }
}

// ---------------------------------------------------------------- counts
__global__ void k_count(float* __restrict__ out) {
    int n = blockIdx.x * 256 + threadIdx.x;      // 128 blocks
    int j = (int)out[OFF_IDX + n];
    atomicAdd(out + OFF_CS + j, 1.0f);
}

// ---------------------------------------------------------------- scan: offsets + chunk table + new_cs
__global__ void k_scan(const float* __restrict__ ema_cs, float* __restrict__ ws,
                       float* __restrict__ out) {
    __shared__ float s[K_CODES];
    int tid = threadIdx.x;                       // 1024
    float cntf = out[OFF_CS + tid];
    int   cnt  = (int)cntf;
    float raw  = ema_cs[tid] * DECAY + 0.01f * cntf;

    s[tid] = cntf;
    __syncthreads();
    for (int off = 1; off < 1024; off <<= 1) {
        float v = (tid >= off) ? s[tid - off] : 0.f;
        __syncthreads();
        s[tid] += v;
        __syncthreads();
    }
    int excl = (int)(s[tid] - cntf);
    ((int*)(ws + WS_OFF))[tid] = excl;
    ((int*)(ws + WS_POS))[tid] = excl;
    ((int*)(ws + WS_CNT))[tid] = cnt;
    __syncthreads();

    int nch = (cnt + CHUNK - 1) / CHUNK;
    s[tid] = (float)nch;
    __syncthreads();
    for (int off = 1; off < 1024; off <<= 1) {
        float v = (tid >= off) ? s[tid - off] : 0.f;
        __syncthreads();
        s[tid] += v;
        __syncthreads();
    }
    int chexcl = (int)s[tid] - nch;
    int* chtab = (int*)(ws + WS_CHTAB);
    for (int k = 0; k < nch; ++k)
        chtab[chexcl + k] = (tid << 16) | k;
    if (tid == 1023) *(int*)(ws + WS_TC) = chexcl + nch;
    __syncthreads();

    s[tid] = raw;
    __syncthreads();
    for (int st = 512; st > 0; st >>= 1) {
        if (tid < st) s[tid] += s[tid + st];
        __syncthreads();
    }
    float ntot = s[0];
    out[OFF_CS + tid] = (raw + EPSV) / (ntot + K_CODES * EPSV) * ntot;
}

// ---------------------------------------------------------------- scatter into buckets
__global__ void k_scatter(const float* __restrict__ out_c, float* __restrict__ ws) {
    int n = blockIdx.x * 256 + threadIdx.x;      // 128 blocks
    int j = (int)out_c[OFF_IDX + n];
    int p = atomicAdd((int*)(ws + WS_POS) + j, 1);
    ((int*)(ws + WS_FIXLIST))[p] = n;
}

// ---------------------------------------------------------------- zero dw accumulator
__global__ void k_zero(float* __restrict__ out) {
    int i = blockIdx.x * 256 + threadIdx.x;      // 256 blocks
    *reinterpret_cast<float4*>(out + OFF_EMAW + i * 4) = (float4){0.f, 0.f, 0.f, 0.f};
}

// ---------------------------------------------------------------- dw partial sums (chunked)
__global__ void k_dw2(const float* __restrict__ ws, float* __restrict__ out) {
    __shared__ int midx[CHUNK];
    const int b = blockIdx.x;                    // 2048 blocks
    if (b >= *(const int*)(ws + WS_TC)) return;
    const int tab = ((const int*)(ws + WS_CHTAB))[b];
    const int j   = tab >> 16;
    const int lc  = tab & 0xffff;
    const int off = ((const int*)(ws + WS_OFF))[j];
    const int cnt = ((const int*)(ws + WS_CNT))[j];
    const int base = lc * CHUNK;
    const int m    = min(CHUNK, cnt - base);
    const int tid  = threadIdx.x;                // 256: d = tid
    if (tid < CHUNK)
        midx[tid] = (tid < m) ? ((const int*)(ws + WS_FIXLIST))[off + base + tid] : 0;
    __syncthreads();
    float acc = 0.f;
    for (int i = 0; i < m; ++i)
        acc += out[OFF_ZQ + (long)midx[i] * 256 + tid];
    atomicAdd(out + OFF_EMAW + j * 256 + tid, acc);
}

// ---------------------------------------------------------------- new_ema_w + new_embedding
__global__ void k_emb2(const float* __restrict__ ema_w, float* __restrict__ out) {
    int i4 = blockIdx.x * 256 + threadIdx.x;     // 256 blocks -> 65536 float4
    int j  = i4 >> 6;
    float4 dw = *reinterpret_cast<float4*>(out + OFF_EMAW + i4 * 4);
    float4 ew = *reinterpret_cast<const float4*>(ema_w + i4 * 4);
    float inv = 1.f / out[OFF_CS + j];
    float4 nw = {ew.x * DECAY + 0.01f * dw.x, ew.y * DECAY + 0.01f * dw.y,
                 ew.z * DECAY + 0.01f * dw.z, ew.w * DECAY + 0.01f * dw.w};
    *reinterpret_cast<float4*>(out + OFF_EMAW + i4 * 4) = nw;
    float4 nb = {nw.x * inv, nw.y * inv, nw.z * inv, nw.w * inv};
    *reinterpret_cast<float4*>(out + OFF_EMB + i4 * 4) = nb;
}

// ---------------------------------------------------------------- z_q + loss
__global__ void k_epi(const float* __restrict__ z, const float* __restrict__ emb,
                      float* __restrict__ out) {
    __shared__ float erows[32][257];
    __shared__ int js[32];
    const int tid = threadIdx.x;                 // 256
    const int n0  = blockIdx.x * 32;             // 1024 blocks
    const int b   = n0 >> 10;
    const int hw0 = n0 & 1023;
    if (tid < 32) js[tid] = (int)out[OFF_IDX + n0 + tid];
    __syncthreads();
    #pragma unroll 4
    for (int r = 0; r < 32; ++r)
        erows[r][tid] = emb[js[r] * D_DIM + tid];
    __syncthreads();
    const long zqb = (long)b * (D_DIM * 1024) + hw0;
    float ls = 0.f;
    #pragma unroll 4
    for (int rep = 0; rep < 32; ++rep) {
        int elem = rep * 256 + tid;
        int d    = elem >> 5;
        int nl   = elem & 31;
        float zq = erows[nl][d];
        float zv = z[zqb + d * 1024 + nl];
        out[OFF_ZQ + zqb + d * 1024 + nl] = zq;
        float df = zq - zv; ls += df * df;
    }
    #pragma unroll
    for (int o = 32; o > 0; o >>= 1) ls += __shfl_xor(ls, o, 64);
    if ((tid & 63) == 0)
        atomicAdd(out + OFF_LOSS, ls * (BETA / (float)(N_VEC * D_DIM)));
}

// ---------------------------------------------------------------- launch
extern "C" void kernel_launch(void* const* d_in, const int* in_sizes, int n_in,
                              void* d_out, int out_size, void* d_ws, size_t ws_size,
                              hipStream_t stream) {
    const float* z      = (const float*)d_in[0];
    const float* emb    = (const float*)d_in[1];
    const float* ema_cs = (const float*)d_in[2];
    const float* ema_w  = (const float*)d_in[3];
    float* out = (float*)d_out;
    float* ws  = (float*)d_ws;                   // ~5.7 MB used

    hipLaunchKernelGGL(k_init,    dim3(64),   dim3(1024), 0, stream, out, ws);
    hipLaunchKernelGGL(k_prep,    dim3(256),  dim3(256),  0, stream, emb, ws);
    hipLaunchKernelGGL(k_prep_b,  dim3(128),  dim3(256),  0, stream, emb, out);
    hipLaunchKernelGGL(k_trans,   dim3(8192), dim3(256),  0, stream, z, out, ws);
    hipLaunchKernelGGL(k_main,    dim3(256),  dim3(512),  0, stream, out, ws);
    hipLaunchKernelGGL(k_merge,   dim3(128),  dim3(256),  0, stream, ws, out);
    hipLaunchKernelGGL(k_fix,     dim3(256),  dim3(256),  0, stream, ws, out);
    hipLaunchKernelGGL(k_count,   dim3(128),  dim3(256),  0, stream, out);
    hipLaunchKernelGGL(k_scan,    dim3(1),    dim3(1024), 0, stream, ema_cs, ws, out);
    hipLaunchKernelGGL(k_scatter, dim3(128),  dim3(256),  0, stream, out, ws);
    hipLaunchKernelGGL(k_zero,    dim3(256),  dim3(256),  0, stream, out);
    hipLaunchKernelGGL(k_dw2,     dim3(2048), dim3(256),  0, stream, ws, out);
    hipLaunchKernelGGL(k_emb2,    dim3(256),  dim3(256),  0, stream, ema_w, out);
    hipLaunchKernelGGL(k_epi,     dim3(1024), dim3(256),  0, stream, z, emb, out);
}